// Round 2
// baseline (12039.965 us; speedup 1.0000x reference)
//
#include <hip/hip_runtime.h>
#include <hip/hip_bf16.h>

// Problem constants (reference: N=100000 nodes, E=1600000 edges, D=H=128).
// Runtime sizes are derived from in_sizes for safety; kernels take them as args.

// ---------------------------------------------------------------- utilities

__global__ __launch_bounds__(256) void zero_u32(unsigned* __restrict__ p, int n) {
  int i = blockIdx.x * 256 + threadIdx.x;
  if (i < n) p[i] = 0u;
}

__global__ __launch_bounds__(256) void deg_count(const int* __restrict__ tgt,
                                                 unsigned* __restrict__ deg, int E) {
  int e = blockIdx.x * 256 + threadIdx.x;
  if (e < E) atomicAdd(&deg[tgt[e]], 1u);
}

__global__ __launch_bounds__(256) void make_dis(const unsigned* __restrict__ deg,
                                                float* __restrict__ dis, int N) {
  int i = blockIdx.x * 256 + threadIdx.x;
  if (i < N) dis[i] = rsqrtf((float)deg[i] + 1.0f);  // deg>=0, +1 self-loop
}

// ------------------------------------------------------------------- GEMM
// out[row][col0 + c] = sum_k A[row][k] * W[k][col0 + c]
// A is [nRows][128] row-major (K always 128). W is [128][nout] row-major.
// grid = (ceil(nRows/64), nout/128). 256 threads, 8x4 micro-tile per thread.
__global__ __launch_bounds__(256) void gemm_k(const float* __restrict__ A,
                                              const float* __restrict__ W,
                                              float* __restrict__ out,
                                              int nRows, int nout) {
  __shared__ float As[64][36];    // +4 pad keeps float4 alignment
  __shared__ float Ws[32][128];
  const int tid  = threadIdx.x;
  const int row0 = blockIdx.x * 64;
  const int col0 = blockIdx.y * 128;
  const bool full = (row0 + 64 <= nRows);   // block-uniform fast path
  const int ty = tid >> 5, tx = tid & 31;
  const int r0 = ty * 8, c0 = tx * 4;
  float acc[8][4] = {};
  for (int kt = 0; kt < 128; kt += 32) {
    // stage A tile 64x32 (512 float4, 2 per thread), coalesced
    if (full) {
#pragma unroll
      for (int j = 0; j < 2; ++j) {
        int chunk = tid + j * 256;
        int r = chunk >> 3, c4 = (chunk & 7) * 4;
        *(float4*)(&As[r][c4]) =
            *(const float4*)(A + (size_t)(row0 + r) * 128 + kt + c4);
      }
    } else {
#pragma unroll
      for (int j = 0; j < 2; ++j) {
        int chunk = tid + j * 256;
        int r = chunk >> 3, c4 = (chunk & 7) * 4;
        float4 v = make_float4(0.f, 0.f, 0.f, 0.f);
        int gr = row0 + r;
        if (gr < nRows) v = *(const float4*)(A + (size_t)gr * 128 + kt + c4);
        *(float4*)(&As[r][c4]) = v;
      }
    }
    // stage W tile 32x128 (1024 float4, 4 per thread), coalesced
#pragma unroll
    for (int j = 0; j < 4; ++j) {
      int chunk = tid + j * 256;
      int wr = chunk >> 5, wc4 = (chunk & 31) * 4;
      *(float4*)(&Ws[wr][wc4]) =
          *(const float4*)(W + (size_t)(kt + wr) * nout + col0 + wc4);
    }
    __syncthreads();
#pragma unroll
    for (int kk = 0; kk < 8; ++kk) {
      const float4 wv0 = *(const float4*)(&Ws[kk * 4 + 0][c0]);
      const float4 wv1 = *(const float4*)(&Ws[kk * 4 + 1][c0]);
      const float4 wv2 = *(const float4*)(&Ws[kk * 4 + 2][c0]);
      const float4 wv3 = *(const float4*)(&Ws[kk * 4 + 3][c0]);
#pragma unroll
      for (int i = 0; i < 8; ++i) {
        const float4 av = *(const float4*)(&As[r0 + i][kk * 4]);
        acc[i][0] += av.x * wv0.x + av.y * wv1.x + av.z * wv2.x + av.w * wv3.x;
        acc[i][1] += av.x * wv0.y + av.y * wv1.y + av.z * wv2.y + av.w * wv3.y;
        acc[i][2] += av.x * wv0.z + av.y * wv1.z + av.z * wv2.z + av.w * wv3.z;
        acc[i][3] += av.x * wv0.w + av.y * wv1.w + av.z * wv2.w + av.w * wv3.w;
      }
    }
    __syncthreads();
  }
#pragma unroll
  for (int i = 0; i < 8; ++i) {
    int gr = row0 + r0 + i;
    if (gr < nRows) {
      float4 v = make_float4(acc[i][0], acc[i][1], acc[i][2], acc[i][3]);
      *(float4*)(out + (size_t)gr * nout + col0 + c0) = v;
    }
  }
}

// --------------------------------------------------------- GCN aggregation

// agg[i][:] = hw[i][:] * dis[i]^2   (self-loop message; also zero-inits agg)
__global__ __launch_bounds__(256) void self_init(const float* __restrict__ hw,
                                                 const float* __restrict__ dis,
                                                 float* __restrict__ agg, int N) {
  int id = blockIdx.x * 256 + threadIdx.x;
  if (id >= N * 32) return;
  int i = id >> 5, c = (id & 31) * 4;
  float s = dis[i];
  s = s * s;
  float4 v = *(const float4*)(hw + (size_t)i * 128 + c);
  v.x *= s; v.y *= s; v.z *= s; v.w *= s;
  *(float4*)(agg + (size_t)i * 128 + c) = v;
}

// agg[tgt] += hw[src] * dis[src]*dis[tgt]   (8 edges / block, 32 lanes/edge)
__global__ __launch_bounds__(256) void scatter_k(const int* __restrict__ src,
                                                 const int* __restrict__ tgt,
                                                 const float* __restrict__ dis,
                                                 const float* __restrict__ hw,
                                                 float* __restrict__ agg, int E) {
  int e = blockIdx.x * 8 + (threadIdx.x >> 5);
  if (e >= E) return;
  int c = (threadIdx.x & 31) * 4;
  int s = src[e], t = tgt[e];
  float coef = dis[s] * dis[t];
  float4 v = *(const float4*)(hw + (size_t)s * 128 + c);
  float* dst = agg + (size_t)t * 128 + c;
  atomicAdd(dst + 0, v.x * coef);
  atomicAdd(dst + 1, v.y * coef);
  atomicAdd(dst + 2, v.z * coef);
  atomicAdd(dst + 3, v.w * coef);
}

// out[i][:] = relu(agg[i][:] + b[:])   (fmaxf also maps NaN->0 like nan_to_num)
__global__ __launch_bounds__(256) void finalize_k(const float* __restrict__ agg,
                                                  const float* __restrict__ bias,
                                                  float* __restrict__ out, int N) {
  int id = blockIdx.x * 256 + threadIdx.x;
  if (id >= N * 32) return;
  int i = id >> 5, c = (id & 31) * 4;
  float4 v = *(const float4*)(agg + (size_t)i * 128 + c);
  const float4 b = *(const float4*)(bias + c);
  v.x = fmaxf(v.x + b.x, 0.f);
  v.y = fmaxf(v.y + b.y, 0.f);
  v.z = fmaxf(v.z + b.z, 0.f);
  v.w = fmaxf(v.w + b.w, 0.f);
  *(float4*)(out + (size_t)i * 128 + c) = v;
}

// -------------------------------------------------------------- edge scorer
// Per 32-edge block:
//   z1[i][j] = relu(A[src_i][j] + B[tgt_i][j] + sb1[j])          j in [0,256)
//   z2 = relu(z1 @ sW2 + sb2)   (32x256 @ 256x128, fp32 tiled GEMM)
//   score = clip(z2 @ sW3 + sb3)
__global__ __launch_bounds__(256) void scorer_k(const float* __restrict__ Amat,
                                                const float* __restrict__ Bmat,
                                                const int* __restrict__ src,
                                                const int* __restrict__ tgt,
                                                const float* __restrict__ sb1,
                                                const float* __restrict__ sW2,
                                                const float* __restrict__ sb2,
                                                const float* __restrict__ sW3,
                                                const float* __restrict__ sb3,
                                                float* __restrict__ score, int E) {
  __shared__ float z1[32][260];   // pad 256->260 keeps float4 alignment
  __shared__ float Ws[32][128];
  const int tid  = threadIdx.x;
  const int lane = tid & 63;
  const int g    = tid >> 6;      // wave id 0..3
  const int e0   = blockIdx.x * 32;

  // per-lane slice of sb1 (lane l always handles cols 4l..4l+3 of z1)
  const float4 bb = *(const float4*)(sb1 + lane * 4);

  // phase A: build z1 tile. Each wave handles 8 edges; one float4/lane per edge.
#pragma unroll
  for (int j = 0; j < 8; ++j) {
    int i = g * 8 + j;
    int e = e0 + i;
    int ec = (e < E) ? e : (E - 1);          // clamp reads; writes guarded later
    int s = src[ec], t = tgt[ec];
    float4 a = *(const float4*)(Amat + (size_t)s * 256 + lane * 4);
    float4 b = *(const float4*)(Bmat + (size_t)t * 256 + lane * 4);
    float4 z;
    z.x = fmaxf(a.x + b.x + bb.x, 0.f);
    z.y = fmaxf(a.y + b.y + bb.y, 0.f);
    z.z = fmaxf(a.z + b.z + bb.z, 0.f);
    z.w = fmaxf(a.w + b.w + bb.w, 0.f);
    *(float4*)(&z1[i][lane * 4]) = z;
  }

  const int ty = tid >> 5, tx = tid & 31;
  const int r0 = ty * 4, c0 = tx * 4;
  const float4 w3 = *(const float4*)(sW3 + c0);
  const float4 b2 = *(const float4*)(sb2 + c0);
  float acc[4][4];
#pragma unroll
  for (int i = 0; i < 4; ++i) {
    acc[i][0] = b2.x; acc[i][1] = b2.y; acc[i][2] = b2.z; acc[i][3] = b2.w;
  }

  // K loop over 256 in tiles of 32 (sW2 tile staged in LDS)
  for (int kt = 0; kt < 256; kt += 32) {
#pragma unroll
    for (int j = 0; j < 4; ++j) {
      int chunk = tid + j * 256;
      int wr = chunk >> 5, wc4 = (chunk & 31) * 4;
      *(float4*)(&Ws[wr][wc4]) =
          *(const float4*)(sW2 + (size_t)(kt + wr) * 128 + wc4);
    }
    __syncthreads();   // covers z1 writes (first iter) + Ws staging
#pragma unroll
    for (int kk = 0; kk < 8; ++kk) {
      const float4 wv0 = *(const float4*)(&Ws[kk * 4 + 0][c0]);
      const float4 wv1 = *(const float4*)(&Ws[kk * 4 + 1][c0]);
      const float4 wv2 = *(const float4*)(&Ws[kk * 4 + 2][c0]);
      const float4 wv3 = *(const float4*)(&Ws[kk * 4 + 3][c0]);
#pragma unroll
      for (int i = 0; i < 4; ++i) {
        const float4 zv = *(const float4*)(&z1[r0 + i][kt + kk * 4]);
        acc[i][0] += zv.x * wv0.x + zv.y * wv1.x + zv.z * wv2.x + zv.w * wv3.x;
        acc[i][1] += zv.x * wv0.y + zv.y * wv1.y + zv.z * wv2.y + zv.w * wv3.y;
        acc[i][2] += zv.x * wv0.z + zv.y * wv1.z + zv.z * wv2.z + zv.w * wv3.z;
        acc[i][3] += zv.x * wv0.w + zv.y * wv1.w + zv.z * wv2.w + zv.w * wv3.w;
      }
    }
    __syncthreads();
  }

  // epilogue: relu(z2) . sW3, reduce over 32 col-group lanes, clip, write
  const float sb3s = sb3[0];
#pragma unroll
  for (int i = 0; i < 4; ++i) {
    float p = fmaxf(acc[i][0], 0.f) * w3.x + fmaxf(acc[i][1], 0.f) * w3.y +
              fmaxf(acc[i][2], 0.f) * w3.z + fmaxf(acc[i][3], 0.f) * w3.w;
#pragma unroll
    for (int m = 16; m; m >>= 1) p += __shfl_xor(p, m, 64);
    if (tx == 0) {
      int e = e0 + r0 + i;
      if (e < E) {
        float v = p + sb3s;
        v = fminf(fmaxf(v, -1e6f), 1e6f);
        if (v != v) v = 0.f;
        score[e] = v;
      }
    }
  }
}

// ------------------------------------------------------------------ launch

extern "C" void kernel_launch(void* const* d_in, const int* in_sizes, int n_in,
                              void* d_out, int out_size, void* d_ws, size_t ws_size,
                              hipStream_t stream) {
  const float* x   = (const float*)d_in[0];
  const int*   ei  = (const int*)d_in[1];
  const float* W1  = (const float*)d_in[2];
  const float* b1  = (const float*)d_in[3];
  const float* W2  = (const float*)d_in[4];
  const float* b2  = (const float*)d_in[5];
  const float* W3  = (const float*)d_in[6];
  const float* b3  = (const float*)d_in[7];
  const float* sW1 = (const float*)d_in[8];
  const float* sb1 = (const float*)d_in[9];
  const float* sW2 = (const float*)d_in[10];
  const float* sb2 = (const float*)d_in[11];
  const float* sW3 = (const float*)d_in[12];
  const float* sb3 = (const float*)d_in[13];

  const int N = in_sizes[0] / 128;   // 100000
  const int E = in_sizes[1] / 2;     // 1600000
  const int* src = ei;
  const int* tgt = ei + E;

  float* out_score = (float*)d_out;
  float* out_emb   = out_score + E;   // output order: (score, node_embs)

  // ws arena: dis[N] | R0 | R1 | R2 | R3  (each R = N*128 floats)
  // layers use R0=h, R1=hw, R2=agg. A = R0..R1 (N*256), B = R2..R3 (N*256).
  float* ws  = (float*)d_ws;
  float* dis = ws;
  float* R0  = ws + N;
  float* R1  = R0 + (size_t)N * 128;
  float* R2  = R1 + (size_t)N * 128;
  unsigned* deg = (unsigned*)R0;      // reused before R0 becomes h

  const dim3 blk(256);
  const int gN    = (N + 255) / 256;
  const int gE    = (E + 255) / 256;
  const int gRows = (N + 63) / 64;
  const int gNel  = (N * 32 + 255) / 256;

  // degree -> dis = 1/sqrt(deg+1)
  zero_u32<<<gN, blk, 0, stream>>>(deg, N);
  deg_count<<<gE, blk, 0, stream>>>(tgt, deg, E);
  make_dis<<<gN, blk, 0, stream>>>(deg, dis, N);

  // ---- GCN layer 1: x -> R0
  gemm_k<<<dim3(gRows, 1), blk, 0, stream>>>(x, W1, R1, N, 128);
  self_init<<<gNel, blk, 0, stream>>>(R1, dis, R2, N);
  scatter_k<<<(E + 7) / 8, blk, 0, stream>>>(src, tgt, dis, R1, R2, E);
  finalize_k<<<gNel, blk, 0, stream>>>(R2, b1, R0, N);
  // ---- GCN layer 2: R0 -> R0
  gemm_k<<<dim3(gRows, 1), blk, 0, stream>>>(R0, W2, R1, N, 128);
  self_init<<<gNel, blk, 0, stream>>>(R1, dis, R2, N);
  scatter_k<<<(E + 7) / 8, blk, 0, stream>>>(src, tgt, dis, R1, R2, E);
  finalize_k<<<gNel, blk, 0, stream>>>(R2, b2, R0, N);
  // ---- GCN layer 3: R0 -> out_emb (node_embs output; relu==nan_to_num-safe)
  gemm_k<<<dim3(gRows, 1), blk, 0, stream>>>(R0, W3, R1, N, 128);
  self_init<<<gNel, blk, 0, stream>>>(R1, dis, R2, N);
  scatter_k<<<(E + 7) / 8, blk, 0, stream>>>(src, tgt, dis, R1, R2, E);
  finalize_k<<<gNel, blk, 0, stream>>>(R2, b3, out_emb, N);

  // ---- scorer: A = emb @ sW1[0:128,:], B = emb @ sW1[128:256,:]
  gemm_k<<<dim3(gRows, 2), blk, 0, stream>>>(out_emb, sW1, R0, N, 256);
  gemm_k<<<dim3(gRows, 2), blk, 0, stream>>>(out_emb, sW1 + 128 * 256, R2, N, 256);
  scorer_k<<<(E + 31) / 32, blk, 0, stream>>>(R0, R2, src, tgt, sb1, sW2, sb2,
                                              sW3, sb3, out_score, E);
}

// Round 5
// 4914.705 us; speedup vs baseline: 2.4498x; 2.4498x over previous
//
#include <hip/hip_runtime.h>
#include <hip/hip_bf16.h>

// GCN (3 layers) + edge-scorer MLP. N=100000, E=1600000, D=H=128.
// R5 == R3/R4 design (never executed due to infra): CSR(tgt) gather
// aggregation, fused agg+bias+relu, CSR-ordered scorer with reg prefetch.

#define SCORER_G 8   // 32-edge tiles per scorer block

// ---------------------------------------------------------------- prep

__global__ __launch_bounds__(256) void zero_i32(int* __restrict__ p, int n) {
  int i = blockIdx.x * 256 + threadIdx.x;
  if (i < n) p[i] = 0;
}

__global__ __launch_bounds__(256) void deg_count(const int* __restrict__ tgt,
                                                 int* __restrict__ deg, int E) {
  int e = blockIdx.x * 256 + threadIdx.x;
  if (e < E) atomicAdd(&deg[tgt[e]], 1);
}

// block-level inclusive scan of deg -> rowptr[i+1] (partial), block sums
__global__ __launch_bounds__(256) void scan1(const int* __restrict__ deg,
                                             int* __restrict__ rowptr,
                                             int* __restrict__ bsum, int N) {
  __shared__ int s[256];
  int tid = threadIdx.x;
  int i = blockIdx.x * 256 + tid;
  int v = (i < N) ? deg[i] : 0;
  s[tid] = v;
  __syncthreads();
  for (int off = 1; off < 256; off <<= 1) {
    int t = (tid >= off) ? s[tid - off] : 0;
    __syncthreads();
    s[tid] += t;
    __syncthreads();
  }
  if (i < N) rowptr[i + 1] = s[tid];
  if (tid == 255) bsum[blockIdx.x] = s[255];
}

// exclusive scan of block sums (nb <= 512) in one block
__global__ __launch_bounds__(512) void scan2(int* __restrict__ bsum, int nb) {
  __shared__ int s[512];
  int tid = threadIdx.x;
  int v = (tid < nb) ? bsum[tid] : 0;
  s[tid] = v;
  __syncthreads();
  for (int off = 1; off < 512; off <<= 1) {
    int t = (tid >= off) ? s[tid - off] : 0;
    __syncthreads();
    s[tid] += t;
    __syncthreads();
  }
  if (tid < nb) bsum[tid] = s[tid] - v;   // exclusive prefix
}

// finalize rowptr, derive cursor (bucket start) and dis = rsqrt(deg+1)
__global__ __launch_bounds__(256) void scan3(int* __restrict__ rowptr,
                                             int* __restrict__ cursor,
                                             const int* __restrict__ bsum,
                                             float* __restrict__ dis, int N) {
  int i = blockIdx.x * 256 + threadIdx.x;
  if (i >= N) return;
  int incl = rowptr[i + 1] + bsum[blockIdx.x];
  rowptr[i + 1] = incl;
  int d = cursor[i];          // cursor currently holds deg
  cursor[i] = incl - d;       // bucket start
  dis[i] = rsqrtf((float)d + 1.0f);
  if (i == 0) rowptr[0] = 0;
}

__global__ __launch_bounds__(256) void fill_k(const int* __restrict__ tgt,
                                              int* __restrict__ cursor,
                                              int* __restrict__ csr_eid, int E) {
  int e = blockIdx.x * 256 + threadIdx.x;
  if (e >= E) return;
  int pos = atomicAdd(&cursor[tgt[e]], 1);
  csr_eid[pos] = e;
}

// ------------------------------------------------------------------- GEMM
// out[row][col0+c] = sum_k A[row][k] * W[k][col0+c];  A:[nRows][128], K=128.
__global__ __launch_bounds__(256) void gemm_k(const float* __restrict__ A,
                                              const float* __restrict__ W,
                                              float* __restrict__ out,
                                              int nRows, int nout) {
  __shared__ float As[64][36];
  __shared__ float Ws[32][128];
  const int tid  = threadIdx.x;
  const int row0 = blockIdx.x * 64;
  const int col0 = blockIdx.y * 128;
  const bool full = (row0 + 64 <= nRows);
  const int ty = tid >> 5, tx = tid & 31;
  const int r0 = ty * 8, c0 = tx * 4;
  float acc[8][4] = {};
  for (int kt = 0; kt < 128; kt += 32) {
    if (full) {
#pragma unroll
      for (int j = 0; j < 2; ++j) {
        int chunk = tid + j * 256;
        int r = chunk >> 3, c4 = (chunk & 7) * 4;
        *(float4*)(&As[r][c4]) =
            *(const float4*)(A + (size_t)(row0 + r) * 128 + kt + c4);
      }
    } else {
#pragma unroll
      for (int j = 0; j < 2; ++j) {
        int chunk = tid + j * 256;
        int r = chunk >> 3, c4 = (chunk & 7) * 4;
        float4 v = make_float4(0.f, 0.f, 0.f, 0.f);
        int gr = row0 + r;
        if (gr < nRows) v = *(const float4*)(A + (size_t)gr * 128 + kt + c4);
        *(float4*)(&As[r][c4]) = v;
      }
    }
#pragma unroll
    for (int j = 0; j < 4; ++j) {
      int chunk = tid + j * 256;
      int wr = chunk >> 5, wc4 = (chunk & 31) * 4;
      *(float4*)(&Ws[wr][wc4]) =
          *(const float4*)(W + (size_t)(kt + wr) * nout + col0 + wc4);
    }
    __syncthreads();
#pragma unroll
    for (int kk = 0; kk < 8; ++kk) {
      const float4 wv0 = *(const float4*)(&Ws[kk * 4 + 0][c0]);
      const float4 wv1 = *(const float4*)(&Ws[kk * 4 + 1][c0]);
      const float4 wv2 = *(const float4*)(&Ws[kk * 4 + 2][c0]);
      const float4 wv3 = *(const float4*)(&Ws[kk * 4 + 3][c0]);
#pragma unroll
      for (int i = 0; i < 8; ++i) {
        const float4 av = *(const float4*)(&As[r0 + i][kk * 4]);
        acc[i][0] += av.x * wv0.x + av.y * wv1.x + av.z * wv2.x + av.w * wv3.x;
        acc[i][1] += av.x * wv0.y + av.y * wv1.y + av.z * wv2.y + av.w * wv3.y;
        acc[i][2] += av.x * wv0.z + av.y * wv1.z + av.z * wv2.z + av.w * wv3.z;
        acc[i][3] += av.x * wv0.w + av.y * wv1.w + av.z * wv2.w + av.w * wv3.w;
      }
    }
    __syncthreads();
  }
#pragma unroll
  for (int i = 0; i < 8; ++i) {
    int gr = row0 + r0 + i;
    if (gr < nRows) {
      float4 v = make_float4(acc[i][0], acc[i][1], acc[i][2], acc[i][3]);
      *(float4*)(out + (size_t)gr * nout + col0 + c0) = v;
    }
  }
}

// ------------------------------------------------- fused GCN aggregation
// out[i] = relu( sum_{e in in(i)} hw[src_e]*dis[src_e]*dis[i]
//              + hw[i]*dis[i]^2 + bias )          one wave per node.
__global__ __launch_bounds__(256) void agg_k(const int* __restrict__ rowptr,
                                             const int* __restrict__ csr_eid,
                                             const int* __restrict__ src0,
                                             const float* __restrict__ dis,
                                             const float* __restrict__ hw,
                                             const float* __restrict__ bias,
                                             float* __restrict__ out, int N) {
  int i = (blockIdx.x * 256 + threadIdx.x) >> 6;
  if (i >= N) return;
  int l = threadIdx.x & 63;
  const float di = dis[i];
  const float2 bb = *(const float2*)(bias + l * 2);
  float2 acc = *(const float2*)(hw + (size_t)i * 128 + l * 2);
  float sc = di * di;
  acc.x *= sc; acc.y *= sc;
  int e = rowptr[i], e1 = rowptr[i + 1];
  for (; e + 1 < e1; e += 2) {           // 2-deep to overlap gather chains
    int eA = csr_eid[e], eB = csr_eid[e + 1];
    int sA = src0[eA], sB = src0[eB];
    float cA = dis[sA] * di, cB = dis[sB] * di;
    const float2 vA = *(const float2*)(hw + (size_t)sA * 128 + l * 2);
    const float2 vB = *(const float2*)(hw + (size_t)sB * 128 + l * 2);
    acc.x += vA.x * cA + vB.x * cB;
    acc.y += vA.y * cA + vB.y * cB;
  }
  if (e < e1) {
    int eA = csr_eid[e];
    int sA = src0[eA];
    float cA = dis[sA] * di;
    const float2 vA = *(const float2*)(hw + (size_t)sA * 128 + l * 2);
    acc.x += vA.x * cA;
    acc.y += vA.y * cA;
  }
  acc.x = fmaxf(acc.x + bb.x, 0.f);
  acc.y = fmaxf(acc.y + bb.y, 0.f);
  *(float2*)(out + (size_t)i * 128 + l * 2) = acc;
}

// -------------------------------------------------------------- edge scorer
// CSR-ordered edges, SCORER_G tiles of 32 edges per block, register prefetch
// of the next tile's A/B gathers issued before the current K-loop (latency
// hides under ~2400 cycles of GEMM). Scores written scattered via csr_eid.
__global__ __launch_bounds__(256, 2) void scorer_k(
    const float* __restrict__ Amat, const float* __restrict__ Bmat,
    const int* __restrict__ csr_eid, const int* __restrict__ src0,
    const int* __restrict__ tgt0, const float* __restrict__ sb1,
    const float* __restrict__ sW2, const float* __restrict__ sb2,
    const float* __restrict__ sW3, const float* __restrict__ sb3,
    float* __restrict__ score, int E) {
  __shared__ float z1[32][256];
  __shared__ float Ws[32][128];
  const int tid  = threadIdx.x;
  const int lane = tid & 63;
  const int wv   = tid >> 6;
  const int ty = tid >> 5, tx = tid & 31;
  const int r0 = ty * 4, c0 = tx * 4;
  const float4 bb  = *(const float4*)(sb1 + lane * 4);
  const float4 w3  = *(const float4*)(sW3 + c0);
  const float4 b2v = *(const float4*)(sb2 + c0);
  const float sb3s = sb3[0];
  const int tile0 = blockIdx.x * SCORER_G;

  float4 ra[8], rb[8];
  {  // prefetch tile 0
    int e0 = tile0 * 32;
#pragma unroll
    for (int j = 0; j < 8; ++j) {
      int e = e0 + wv * 8 + j;
      if (e >= E) e = E - 1;
      int eid = csr_eid[e];
      int s = src0[eid], t = tgt0[eid];
      ra[j] = *(const float4*)(Amat + (size_t)s * 256 + lane * 4);
      rb[j] = *(const float4*)(Bmat + (size_t)t * 256 + lane * 4);
    }
  }

  for (int g = 0; g < SCORER_G; ++g) {
    const int e0 = (tile0 + g) * 32;
    if (e0 >= E) break;                      // uniform across block

    // write z1 tile from prefetched regs (relu(A+B+sb1))
#pragma unroll
    for (int j = 0; j < 8; ++j) {
      int i = wv * 8 + j;
      float4 z;
      z.x = fmaxf(ra[j].x + rb[j].x + bb.x, 0.f);
      z.y = fmaxf(ra[j].y + rb[j].y + bb.y, 0.f);
      z.z = fmaxf(ra[j].z + rb[j].z + bb.z, 0.f);
      z.w = fmaxf(ra[j].w + rb[j].w + bb.w, 0.f);
      *(float4*)(&z1[i][lane * 4]) = z;
    }

    // issue next tile's gathers; they stay in flight across the K-loop
    if (g + 1 < SCORER_G && (tile0 + g + 1) * 32 < E) {
      int en0 = (tile0 + g + 1) * 32;
#pragma unroll
      for (int j = 0; j < 8; ++j) {
        int e = en0 + wv * 8 + j;
        if (e >= E) e = E - 1;
        int eid = csr_eid[e];
        int s = src0[eid], t = tgt0[eid];
        ra[j] = *(const float4*)(Amat + (size_t)s * 256 + lane * 4);
        rb[j] = *(const float4*)(Bmat + (size_t)t * 256 + lane * 4);
      }
    }

    float acc[4][4];
#pragma unroll
    for (int i = 0; i < 4; ++i) {
      acc[i][0] = b2v.x; acc[i][1] = b2v.y; acc[i][2] = b2v.z; acc[i][3] = b2v.w;
    }

    for (int kt = 0; kt < 256; kt += 32) {
#pragma unroll
      for (int j = 0; j < 4; ++j) {
        int chunk = tid + j * 256;
        int wr = chunk >> 5, wc4 = (chunk & 31) * 4;
        *(float4*)(&Ws[wr][wc4]) =
            *(const float4*)(sW2 + (size_t)(kt + wr) * 128 + wc4);
      }
      __syncthreads();   // covers z1 writes (first kt) + Ws staging
#pragma unroll
      for (int kk = 0; kk < 8; ++kk) {
        const float4 wv0 = *(const float4*)(&Ws[kk * 4 + 0][c0]);
        const float4 wv1 = *(const float4*)(&Ws[kk * 4 + 1][c0]);
        const float4 wv2 = *(const float4*)(&Ws[kk * 4 + 2][c0]);
        const float4 wv3 = *(const float4*)(&Ws[kk * 4 + 3][c0]);
#pragma unroll
        for (int i = 0; i < 4; ++i) {
          const float4 zv = *(const float4*)(&z1[r0 + i][kt + kk * 4]);
          acc[i][0] += zv.x * wv0.x + zv.y * wv1.x + zv.z * wv2.x + zv.w * wv3.x;
          acc[i][1] += zv.x * wv0.y + zv.y * wv1.y + zv.z * wv2.y + zv.w * wv3.y;
          acc[i][2] += zv.x * wv0.z + zv.y * wv1.z + zv.z * wv2.z + zv.w * wv3.z;
          acc[i][3] += zv.x * wv0.w + zv.y * wv1.w + zv.z * wv2.w + zv.w * wv3.w;
        }
      }
      __syncthreads();   // all z1/Ws reads done before next staging / next tile
    }

    // epilogue: relu(z2).sW3 reduce over 32 lanes, clip, scatter to score[eid]
#pragma unroll
    for (int i = 0; i < 4; ++i) {
      float p = fmaxf(acc[i][0], 0.f) * w3.x + fmaxf(acc[i][1], 0.f) * w3.y +
                fmaxf(acc[i][2], 0.f) * w3.z + fmaxf(acc[i][3], 0.f) * w3.w;
#pragma unroll
      for (int m = 16; m; m >>= 1) p += __shfl_xor(p, m, 64);
      if (tx == 0) {
        int e = e0 + r0 + i;
        if (e < E) {
          float v = p + sb3s;
          v = fminf(fmaxf(v, -1e6f), 1e6f);
          if (v != v) v = 0.f;
          score[csr_eid[e]] = v;
        }
      }
    }
  }
}

// ------------------------------------------------------------------ launch

extern "C" void kernel_launch(void* const* d_in, const int* in_sizes, int n_in,
                              void* d_out, int out_size, void* d_ws, size_t ws_size,
                              hipStream_t stream) {
  const float* x   = (const float*)d_in[0];
  const int*   ei  = (const int*)d_in[1];
  const float* W1  = (const float*)d_in[2];
  const float* b1  = (const float*)d_in[3];
  const float* W2  = (const float*)d_in[4];
  const float* b2  = (const float*)d_in[5];
  const float* W3  = (const float*)d_in[6];
  const float* b3  = (const float*)d_in[7];
  const float* sW1 = (const float*)d_in[8];
  const float* sb1 = (const float*)d_in[9];
  const float* sW2 = (const float*)d_in[10];
  const float* sb2 = (const float*)d_in[11];
  const float* sW3 = (const float*)d_in[12];
  const float* sb3 = (const float*)d_in[13];

  const int N = in_sizes[0] / 128;   // 100000
  const int E = in_sizes[1] / 2;     // 1600000
  const int* src0 = ei;
  const int* tgt0 = ei + E;

  float* out_score = (float*)d_out;
  float* out_emb   = out_score + E;   // output order: (score, node_embs)

  // ws arena (floats):
  //   dis[N] | rowptr[N+4] | csr_eid[E] | Abuf[N*256] | Bbuf[N*256]
  // cursor/bsum overlay the start of Abuf (only live during CSR build,
  // which completes before Abuf's first write).
  float* ws = (float*)d_ws;
  float* dis     = ws;
  int*   rowptr  = (int*)(dis + N);
  int*   csr_eid = rowptr + (N + 4);
  float* Abuf    = (float*)(csr_eid + E);
  float* Bbuf    = Abuf + (size_t)N * 256;
  int*   cursor  = (int*)Abuf;
  int*   bsum    = cursor + N;
  float* hw      = Abuf;              // layer scratch (first N*128 of Abuf)

  const dim3 blk(256);
  const int gN  = (N + 255) / 256;    // 391 (= nb for scan)
  const int gE  = (E + 255) / 256;
  const int gRows = (N + 63) / 64;
  const int gAgg  = (N * 64 + 255) / 256;
  const int nTiles = (E + 31) / 32;
  const int gScore = (nTiles + SCORER_G - 1) / SCORER_G;

  // ---- CSR build: deg -> rowptr -> cursor/dis -> csr_eid
  zero_i32<<<gN, blk, 0, stream>>>(cursor, N);          // cursor = deg
  deg_count<<<gE, blk, 0, stream>>>(tgt0, cursor, E);
  scan1<<<gN, blk, 0, stream>>>(cursor, rowptr, bsum, N);
  scan2<<<1, 512, 0, stream>>>(bsum, gN);
  scan3<<<gN, blk, 0, stream>>>(rowptr, cursor, bsum, dis, N);
  fill_k<<<gE, blk, 0, stream>>>(tgt0, cursor, csr_eid, E);

  // ---- GCN layers (gemm -> fused gather-agg+bias+relu), ping via out_emb
  gemm_k<<<dim3(gRows, 1), blk, 0, stream>>>(x, W1, hw, N, 128);
  agg_k<<<gAgg, blk, 0, stream>>>(rowptr, csr_eid, src0, dis, hw, b1, out_emb, N);
  gemm_k<<<dim3(gRows, 1), blk, 0, stream>>>(out_emb, W2, hw, N, 128);
  agg_k<<<gAgg, blk, 0, stream>>>(rowptr, csr_eid, src0, dis, hw, b2, out_emb, N);
  gemm_k<<<dim3(gRows, 1), blk, 0, stream>>>(out_emb, W3, hw, N, 128);
  agg_k<<<gAgg, blk, 0, stream>>>(rowptr, csr_eid, src0, dis, hw, b3, out_emb, N);

  // ---- scorer prep: A = emb @ sW1[0:128,:], B = emb @ sW1[128:256,:]
  gemm_k<<<dim3(gRows, 2), blk, 0, stream>>>(out_emb, sW1, Abuf, N, 256);
  gemm_k<<<dim3(gRows, 2), blk, 0, stream>>>(out_emb, sW1 + 128 * 256, Bbuf, N, 256);

  // ---- scorer (CSR edge order, prefetched gathers)
  scorer_k<<<gScore, blk, 0, stream>>>(Abuf, Bbuf, csr_eid, src0, tgt0,
                                       sb1, sW2, sb2, sW3, sb3, out_score, E);
}

// Round 9
// 4675.649 us; speedup vs baseline: 2.5750x; 1.0511x over previous
//
#include <hip/hip_runtime.h>
#include <hip/hip_bf16.h>

// GCN (3 layers) + edge-scorer MLP. N=100000, E=1600000, D=H=128.
// R9 == R6/R7/R8 design (never executed due to infra): scorer register-
// prefetch removed (R5 measured it spilling: 4.1 GB scratch writes). Scorer:
// 512 threads, 64-edge tiles, direct CSR-ordered gathers into z1, Ws staged
// in 16-row slices (72 KB LDS -> 2 blocks/CU, 16 waves/CU TLP), VGPR<=128.

#define SCORER_G 4   // 64-edge tiles per scorer block

// ---------------------------------------------------------------- prep

__global__ __launch_bounds__(256) void zero_i32(int* __restrict__ p, int n) {
  int i = blockIdx.x * 256 + threadIdx.x;
  if (i < n) p[i] = 0;
}

__global__ __launch_bounds__(256) void deg_count(const int* __restrict__ tgt,
                                                 int* __restrict__ deg, int E) {
  int e = blockIdx.x * 256 + threadIdx.x;
  if (e < E) atomicAdd(&deg[tgt[e]], 1);
}

// block-level inclusive scan of deg -> rowptr[i+1] (partial), block sums
__global__ __launch_bounds__(256) void scan1(const int* __restrict__ deg,
                                             int* __restrict__ rowptr,
                                             int* __restrict__ bsum, int N) {
  __shared__ int s[256];
  int tid = threadIdx.x;
  int i = blockIdx.x * 256 + tid;
  int v = (i < N) ? deg[i] : 0;
  s[tid] = v;
  __syncthreads();
  for (int off = 1; off < 256; off <<= 1) {
    int t = (tid >= off) ? s[tid - off] : 0;
    __syncthreads();
    s[tid] += t;
    __syncthreads();
  }
  if (i < N) rowptr[i + 1] = s[tid];
  if (tid == 255) bsum[blockIdx.x] = s[255];
}

// exclusive scan of block sums (nb <= 512) in one block
__global__ __launch_bounds__(512) void scan2(int* __restrict__ bsum, int nb) {
  __shared__ int s[512];
  int tid = threadIdx.x;
  int v = (tid < nb) ? bsum[tid] : 0;
  s[tid] = v;
  __syncthreads();
  for (int off = 1; off < 512; off <<= 1) {
    int t = (tid >= off) ? s[tid - off] : 0;
    __syncthreads();
    s[tid] += t;
    __syncthreads();
  }
  if (tid < nb) bsum[tid] = s[tid] - v;   // exclusive prefix
}

// finalize rowptr, derive cursor (bucket start) and dis = rsqrt(deg+1)
__global__ __launch_bounds__(256) void scan3(int* __restrict__ rowptr,
                                             int* __restrict__ cursor,
                                             const int* __restrict__ bsum,
                                             float* __restrict__ dis, int N) {
  int i = blockIdx.x * 256 + threadIdx.x;
  if (i >= N) return;
  int incl = rowptr[i + 1] + bsum[blockIdx.x];
  rowptr[i + 1] = incl;
  int d = cursor[i];          // cursor currently holds deg
  cursor[i] = incl - d;       // bucket start
  dis[i] = rsqrtf((float)d + 1.0f);
  if (i == 0) rowptr[0] = 0;
}

__global__ __launch_bounds__(256) void fill_k(const int* __restrict__ tgt,
                                              int* __restrict__ cursor,
                                              int* __restrict__ csr_eid, int E) {
  int e = blockIdx.x * 256 + threadIdx.x;
  if (e >= E) return;
  int pos = atomicAdd(&cursor[tgt[e]], 1);
  csr_eid[pos] = e;
}

// ------------------------------------------------------------------- GEMM
// out[row][col0+c] = sum_k A[row][k] * W[k][col0+c];  A:[nRows][128], K=128.
__global__ __launch_bounds__(256) void gemm_k(const float* __restrict__ A,
                                              const float* __restrict__ W,
                                              float* __restrict__ out,
                                              int nRows, int nout) {
  __shared__ float As[64][36];
  __shared__ float Ws[32][128];
  const int tid  = threadIdx.x;
  const int row0 = blockIdx.x * 64;
  const int col0 = blockIdx.y * 128;
  const bool full = (row0 + 64 <= nRows);
  const int ty = tid >> 5, tx = tid & 31;
  const int r0 = ty * 8, c0 = tx * 4;
  float acc[8][4] = {};
  for (int kt = 0; kt < 128; kt += 32) {
    if (full) {
#pragma unroll
      for (int j = 0; j < 2; ++j) {
        int chunk = tid + j * 256;
        int r = chunk >> 3, c4 = (chunk & 7) * 4;
        *(float4*)(&As[r][c4]) =
            *(const float4*)(A + (size_t)(row0 + r) * 128 + kt + c4);
      }
    } else {
#pragma unroll
      for (int j = 0; j < 2; ++j) {
        int chunk = tid + j * 256;
        int r = chunk >> 3, c4 = (chunk & 7) * 4;
        float4 v = make_float4(0.f, 0.f, 0.f, 0.f);
        int gr = row0 + r;
        if (gr < nRows) v = *(const float4*)(A + (size_t)gr * 128 + kt + c4);
        *(float4*)(&As[r][c4]) = v;
      }
    }
#pragma unroll
    for (int j = 0; j < 4; ++j) {
      int chunk = tid + j * 256;
      int wr = chunk >> 5, wc4 = (chunk & 31) * 4;
      *(float4*)(&Ws[wr][wc4]) =
          *(const float4*)(W + (size_t)(kt + wr) * nout + col0 + wc4);
    }
    __syncthreads();
#pragma unroll
    for (int kk = 0; kk < 8; ++kk) {
      const float4 wv0 = *(const float4*)(&Ws[kk * 4 + 0][c0]);
      const float4 wv1 = *(const float4*)(&Ws[kk * 4 + 1][c0]);
      const float4 wv2 = *(const float4*)(&Ws[kk * 4 + 2][c0]);
      const float4 wv3 = *(const float4*)(&Ws[kk * 4 + 3][c0]);
#pragma unroll
      for (int i = 0; i < 8; ++i) {
        const float4 av = *(const float4*)(&As[r0 + i][kk * 4]);
        acc[i][0] += av.x * wv0.x + av.y * wv1.x + av.z * wv2.x + av.w * wv3.x;
        acc[i][1] += av.x * wv0.y + av.y * wv1.y + av.z * wv2.y + av.w * wv3.y;
        acc[i][2] += av.x * wv0.z + av.y * wv1.z + av.z * wv2.z + av.w * wv3.z;
        acc[i][3] += av.x * wv0.w + av.y * wv1.w + av.z * wv2.w + av.w * wv3.w;
      }
    }
    __syncthreads();
  }
#pragma unroll
  for (int i = 0; i < 8; ++i) {
    int gr = row0 + r0 + i;
    if (gr < nRows) {
      float4 v = make_float4(acc[i][0], acc[i][1], acc[i][2], acc[i][3]);
      *(float4*)(out + (size_t)gr * nout + col0 + c0) = v;
    }
  }
}

// ------------------------------------------------- fused GCN aggregation
// out[i] = relu( sum_{e in in(i)} hw[src_e]*dis[src_e]*dis[i]
//              + hw[i]*dis[i]^2 + bias )          one wave per node.
__global__ __launch_bounds__(256) void agg_k(const int* __restrict__ rowptr,
                                             const int* __restrict__ csr_eid,
                                             const int* __restrict__ src0,
                                             const float* __restrict__ dis,
                                             const float* __restrict__ hw,
                                             const float* __restrict__ bias,
                                             float* __restrict__ out, int N) {
  int i = (blockIdx.x * 256 + threadIdx.x) >> 6;
  if (i >= N) return;
  int l = threadIdx.x & 63;
  const float di = dis[i];
  const float2 bb = *(const float2*)(bias + l * 2);
  float2 acc = *(const float2*)(hw + (size_t)i * 128 + l * 2);
  float sc = di * di;
  acc.x *= sc; acc.y *= sc;
  int e = rowptr[i], e1 = rowptr[i + 1];
  for (; e + 1 < e1; e += 2) {           // 2-deep to overlap gather chains
    int eA = csr_eid[e], eB = csr_eid[e + 1];
    int sA = src0[eA], sB = src0[eB];
    float cA = dis[sA] * di, cB = dis[sB] * di;
    const float2 vA = *(const float2*)(hw + (size_t)sA * 128 + l * 2);
    const float2 vB = *(const float2*)(hw + (size_t)sB * 128 + l * 2);
    acc.x += vA.x * cA + vB.x * cB;
    acc.y += vA.y * cA + vB.y * cB;
  }
  if (e < e1) {
    int eA = csr_eid[e];
    int sA = src0[eA];
    float cA = dis[sA] * di;
    const float2 vA = *(const float2*)(hw + (size_t)sA * 128 + l * 2);
    acc.x += vA.x * cA;
    acc.y += vA.y * cA;
  }
  acc.x = fmaxf(acc.x + bb.x, 0.f);
  acc.y = fmaxf(acc.y + bb.y, 0.f);
  *(float2*)(out + (size_t)i * 128 + l * 2) = acc;
}

// -------------------------------------------------------------- edge scorer
// 512 threads, 64-edge tiles, CSR edge order. Direct gathers into z1 (no
// cross-barrier register state -> no spills). z1 64KB + Ws 8KB = 72KB LDS
// -> 2 blocks/CU (16 waves/CU TLP). Per-thread 4x4 micro-tile, kt-step 16.
__global__ __launch_bounds__(512, 4) void scorer_k(
    const float* __restrict__ Amat, const float* __restrict__ Bmat,
    const int* __restrict__ csr_eid, const int* __restrict__ src0,
    const int* __restrict__ tgt0, const float* __restrict__ sb1,
    const float* __restrict__ sW2, const float* __restrict__ sb2,
    const float* __restrict__ sW3, const float* __restrict__ sb3,
    float* __restrict__ score, int E) {
  __shared__ float z1[64][256];    // 64 KB
  __shared__ float Ws[16][128];    // 8 KB
  const int tid  = threadIdx.x;
  const int lane = tid & 63;
  const int wv   = tid >> 6;       // wave 0..7
  const int ty   = tid >> 5;       // 0..15
  const int tx   = tid & 31;
  const int r0 = ty * 4, c0 = tx * 4;
  const float4 bb  = *(const float4*)(sb1 + lane * 4);
  const float4 w3  = *(const float4*)(sW3 + c0);
  const float4 b2v = *(const float4*)(sb2 + c0);
  const float sb3s = sb3[0];

  for (int g = 0; g < SCORER_G; ++g) {
    const int e0 = (blockIdx.x * SCORER_G + g) * 64;
    if (e0 >= E) break;                     // uniform across block

    // build z1 tile: each wave gathers+combines 8 edges (1 float4/lane/edge)
#pragma unroll
    for (int j = 0; j < 8; ++j) {
      int e = e0 + wv * 8 + j;
      if (e >= E) e = E - 1;                // clamp reads; writes guarded later
      int eid = csr_eid[e];
      int s = src0[eid], t = tgt0[eid];
      float4 a = *(const float4*)(Amat + (size_t)s * 256 + lane * 4);
      float4 b = *(const float4*)(Bmat + (size_t)t * 256 + lane * 4);
      float4 z;
      z.x = fmaxf(a.x + b.x + bb.x, 0.f);
      z.y = fmaxf(a.y + b.y + bb.y, 0.f);
      z.z = fmaxf(a.z + b.z + bb.z, 0.f);
      z.w = fmaxf(a.w + b.w + bb.w, 0.f);
      *(float4*)(&z1[wv * 8 + j][lane * 4]) = z;
    }

    float acc[4][4];
#pragma unroll
    for (int i = 0; i < 4; ++i) {
      acc[i][0] = b2v.x; acc[i][1] = b2v.y; acc[i][2] = b2v.z; acc[i][3] = b2v.w;
    }

    // K loop over 256 in slices of 16 (Ws: 16x128, one float4 per thread)
    for (int kt = 0; kt < 256; kt += 16) {
      *(float4*)(&Ws[ty][tx * 4]) =
          *(const float4*)(sW2 + (size_t)(kt + ty) * 128 + tx * 4);
      __syncthreads();   // covers z1 writes (first kt) + Ws staging
#pragma unroll
      for (int kk = 0; kk < 4; ++kk) {
        const float4 wv0 = *(const float4*)(&Ws[kk * 4 + 0][c0]);
        const float4 wv1 = *(const float4*)(&Ws[kk * 4 + 1][c0]);
        const float4 wv2 = *(const float4*)(&Ws[kk * 4 + 2][c0]);
        const float4 wv3 = *(const float4*)(&Ws[kk * 4 + 3][c0]);
#pragma unroll
        for (int i = 0; i < 4; ++i) {
          const float4 zv = *(const float4*)(&z1[r0 + i][kt + kk * 4]);
          acc[i][0] += zv.x * wv0.x + zv.y * wv1.x + zv.z * wv2.x + zv.w * wv3.x;
          acc[i][1] += zv.x * wv0.y + zv.y * wv1.y + zv.z * wv2.y + zv.w * wv3.y;
          acc[i][2] += zv.x * wv0.z + zv.y * wv1.z + zv.z * wv2.z + zv.w * wv3.z;
          acc[i][3] += zv.x * wv0.w + zv.y * wv1.w + zv.z * wv2.w + zv.w * wv3.w;
        }
      }
      __syncthreads();   // all Ws/z1 reads done before next stage / next tile
    }

    // epilogue: relu(z2).sW3, reduce over 32 col lanes, clip, scatter write
#pragma unroll
    for (int i = 0; i < 4; ++i) {
      float p = fmaxf(acc[i][0], 0.f) * w3.x + fmaxf(acc[i][1], 0.f) * w3.y +
                fmaxf(acc[i][2], 0.f) * w3.z + fmaxf(acc[i][3], 0.f) * w3.w;
#pragma unroll
      for (int m = 16; m; m >>= 1) p += __shfl_xor(p, m, 64);
      if (tx == 0) {
        int e = e0 + r0 + i;
        if (e < E) {
          float v = p + sb3s;
          v = fminf(fmaxf(v, -1e6f), 1e6f);
          if (v != v) v = 0.f;
          score[csr_eid[e]] = v;
        }
      }
    }
  }
}

// ------------------------------------------------------------------ launch

extern "C" void kernel_launch(void* const* d_in, const int* in_sizes, int n_in,
                              void* d_out, int out_size, void* d_ws, size_t ws_size,
                              hipStream_t stream) {
  const float* x   = (const float*)d_in[0];
  const int*   ei  = (const int*)d_in[1];
  const float* W1  = (const float*)d_in[2];
  const float* b1  = (const float*)d_in[3];
  const float* W2  = (const float*)d_in[4];
  const float* b2  = (const float*)d_in[5];
  const float* W3  = (const float*)d_in[6];
  const float* b3  = (const float*)d_in[7];
  const float* sW1 = (const float*)d_in[8];
  const float* sb1 = (const float*)d_in[9];
  const float* sW2 = (const float*)d_in[10];
  const float* sb2 = (const float*)d_in[11];
  const float* sW3 = (const float*)d_in[12];
  const float* sb3 = (const float*)d_in[13];

  const int N = in_sizes[0] / 128;   // 100000
  const int E = in_sizes[1] / 2;     // 1600000
  const int* src0 = ei;
  const int* tgt0 = ei + E;

  float* out_score = (float*)d_out;
  float* out_emb   = out_score + E;   // output order: (score, node_embs)

  // ws arena (floats):
  //   dis[N] | rowptr[N+4] | csr_eid[E] | Abuf[N*256] | Bbuf[N*256]
  // cursor/bsum overlay the start of Abuf (only live during CSR build,
  // which completes before Abuf's first write).
  float* ws = (float*)d_ws;
  float* dis     = ws;
  int*   rowptr  = (int*)(dis + N);
  int*   csr_eid = rowptr + (N + 4);
  float* Abuf    = (float*)(csr_eid + E);
  float* Bbuf    = Abuf + (size_t)N * 256;
  int*   cursor  = (int*)Abuf;
  int*   bsum    = cursor + N;
  float* hw      = Abuf;              // layer scratch (first N*128 of Abuf)

  const dim3 blk(256);
  const int gN  = (N + 255) / 256;    // 391 (= nb for scan)
  const int gE  = (E + 255) / 256;
  const int gRows = (N + 63) / 64;
  const int gAgg  = (N * 64 + 255) / 256;
  const int nT64  = (E + 63) / 64;
  const int gScore = (nT64 + SCORER_G - 1) / SCORER_G;

  // ---- CSR build: deg -> rowptr -> cursor/dis -> csr_eid
  zero_i32<<<gN, blk, 0, stream>>>(cursor, N);          // cursor = deg
  deg_count<<<gE, blk, 0, stream>>>(tgt0, cursor, E);
  scan1<<<gN, blk, 0, stream>>>(cursor, rowptr, bsum, N);
  scan2<<<1, 512, 0, stream>>>(bsum, gN);
  scan3<<<gN, blk, 0, stream>>>(rowptr, cursor, bsum, dis, N);
  fill_k<<<gE, blk, 0, stream>>>(tgt0, cursor, csr_eid, E);

  // ---- GCN layers (gemm -> fused gather-agg+bias+relu), ping via out_emb
  gemm_k<<<dim3(gRows, 1), blk, 0, stream>>>(x, W1, hw, N, 128);
  agg_k<<<gAgg, blk, 0, stream>>>(rowptr, csr_eid, src0, dis, hw, b1, out_emb, N);
  gemm_k<<<dim3(gRows, 1), blk, 0, stream>>>(out_emb, W2, hw, N, 128);
  agg_k<<<gAgg, blk, 0, stream>>>(rowptr, csr_eid, src0, dis, hw, b2, out_emb, N);
  gemm_k<<<dim3(gRows, 1), blk, 0, stream>>>(out_emb, W3, hw, N, 128);
  agg_k<<<gAgg, blk, 0, stream>>>(rowptr, csr_eid, src0, dis, hw, b3, out_emb, N);

  // ---- scorer prep: A = emb @ sW1[0:128,:], B = emb @ sW1[128:256,:]
  gemm_k<<<dim3(gRows, 2), blk, 0, stream>>>(out_emb, sW1, Abuf, N, 256);
  gemm_k<<<dim3(gRows, 2), blk, 0, stream>>>(out_emb, sW1 + 128 * 256, Bbuf, N, 256);

  // ---- scorer (CSR edge order, direct gathers, 64-edge tiles)
  scorer_k<<<gScore, dim3(512), 0, stream>>>(Abuf, Bbuf, csr_eid, src0, tgt0,
                                             sb1, sW2, sb2, sW3, sb3,
                                             out_score, E);
}

// Round 12
// 3086.680 us; speedup vs baseline: 3.9006x; 1.5148x over previous
//
#include <hip/hip_runtime.h>
#include <hip/hip_bf16.h>

// GCN (3 layers) + edge-scorer MLP. N=100000, E=1600000, D=H=128.
// R12 == R10/R11 design (never executed due to infra): scorer z1@sW2 GEMM on
// MFMA (split-bf16, 3 products ~ fp32 accuracy). z1 in LDS as bf16 hi/lo,
// XOR-swizzled (T2); sW2 pre-transposed+split to 128KB global (L2-hot),
// B-fragments read straight from L2 -> 3 barriers/tile. Rest == R9.

#define SCORER_G 4   // 64-edge tiles per scorer block

typedef __attribute__((ext_vector_type(8))) short bf16x8;
typedef __attribute__((ext_vector_type(4))) float f32x4;

__device__ __forceinline__ unsigned short f2bf(float x) {   // RNE f32->bf16
  unsigned u = __float_as_uint(x);
  return (unsigned short)((u + 0x7FFFu + ((u >> 16) & 1u)) >> 16);
}
__device__ __forceinline__ float bf2f(unsigned short b) {
  return __uint_as_float(((unsigned)b) << 16);
}

// ---------------------------------------------------------------- prep

__global__ __launch_bounds__(256) void zero_i32(int* __restrict__ p, int n) {
  int i = blockIdx.x * 256 + threadIdx.x;
  if (i < n) p[i] = 0;
}

__global__ __launch_bounds__(256) void deg_count(const int* __restrict__ tgt,
                                                 int* __restrict__ deg, int E) {
  int e = blockIdx.x * 256 + threadIdx.x;
  if (e < E) atomicAdd(&deg[tgt[e]], 1);
}

__global__ __launch_bounds__(256) void scan1(const int* __restrict__ deg,
                                             int* __restrict__ rowptr,
                                             int* __restrict__ bsum, int N) {
  __shared__ int s[256];
  int tid = threadIdx.x;
  int i = blockIdx.x * 256 + tid;
  int v = (i < N) ? deg[i] : 0;
  s[tid] = v;
  __syncthreads();
  for (int off = 1; off < 256; off <<= 1) {
    int t = (tid >= off) ? s[tid - off] : 0;
    __syncthreads();
    s[tid] += t;
    __syncthreads();
  }
  if (i < N) rowptr[i + 1] = s[tid];
  if (tid == 255) bsum[blockIdx.x] = s[255];
}

__global__ __launch_bounds__(512) void scan2(int* __restrict__ bsum, int nb) {
  __shared__ int s[512];
  int tid = threadIdx.x;
  int v = (tid < nb) ? bsum[tid] : 0;
  s[tid] = v;
  __syncthreads();
  for (int off = 1; off < 512; off <<= 1) {
    int t = (tid >= off) ? s[tid - off] : 0;
    __syncthreads();
    s[tid] += t;
    __syncthreads();
  }
  if (tid < nb) bsum[tid] = s[tid] - v;   // exclusive prefix
}

__global__ __launch_bounds__(256) void scan3(int* __restrict__ rowptr,
                                             int* __restrict__ cursor,
                                             const int* __restrict__ bsum,
                                             float* __restrict__ dis, int N) {
  int i = blockIdx.x * 256 + threadIdx.x;
  if (i >= N) return;
  int incl = rowptr[i + 1] + bsum[blockIdx.x];
  rowptr[i + 1] = incl;
  int d = cursor[i];          // cursor currently holds deg
  cursor[i] = incl - d;       // bucket start
  dis[i] = rsqrtf((float)d + 1.0f);
  if (i == 0) rowptr[0] = 0;
}

__global__ __launch_bounds__(256) void fill_k(const int* __restrict__ tgt,
                                              int* __restrict__ cursor,
                                              int* __restrict__ csr_eid, int E) {
  int e = blockIdx.x * 256 + threadIdx.x;
  if (e >= E) return;
  int pos = atomicAdd(&cursor[tgt[e]], 1);
  csr_eid[pos] = e;
}

// transpose+split sW2[256][128] -> Wth/Wtl[128][256] bf16 (hi/lo residual)
__global__ __launch_bounds__(256) void wsplit_k(const float* __restrict__ sW2,
                                                unsigned short* __restrict__ Wth,
                                                unsigned short* __restrict__ Wtl) {
  int id = blockIdx.x * 256 + threadIdx.x;   // id = n*256 + k
  if (id >= 128 * 256) return;
  int n = id >> 8, k = id & 255;
  float v = sW2[k * 128 + n];
  unsigned short h = f2bf(v);
  Wth[id] = h;
  Wtl[id] = f2bf(v - bf2f(h));
}

// ------------------------------------------------------------------- GEMM
__global__ __launch_bounds__(256) void gemm_k(const float* __restrict__ A,
                                              const float* __restrict__ W,
                                              float* __restrict__ out,
                                              int nRows, int nout) {
  __shared__ float As[64][36];
  __shared__ float Ws[32][128];
  const int tid  = threadIdx.x;
  const int row0 = blockIdx.x * 64;
  const int col0 = blockIdx.y * 128;
  const bool full = (row0 + 64 <= nRows);
  const int ty = tid >> 5, tx = tid & 31;
  const int r0 = ty * 8, c0 = tx * 4;
  float acc[8][4] = {};
  for (int kt = 0; kt < 128; kt += 32) {
    if (full) {
#pragma unroll
      for (int j = 0; j < 2; ++j) {
        int chunk = tid + j * 256;
        int r = chunk >> 3, c4 = (chunk & 7) * 4;
        *(float4*)(&As[r][c4]) =
            *(const float4*)(A + (size_t)(row0 + r) * 128 + kt + c4);
      }
    } else {
#pragma unroll
      for (int j = 0; j < 2; ++j) {
        int chunk = tid + j * 256;
        int r = chunk >> 3, c4 = (chunk & 7) * 4;
        float4 v = make_float4(0.f, 0.f, 0.f, 0.f);
        int gr = row0 + r;
        if (gr < nRows) v = *(const float4*)(A + (size_t)gr * 128 + kt + c4);
        *(float4*)(&As[r][c4]) = v;
      }
    }
#pragma unroll
    for (int j = 0; j < 4; ++j) {
      int chunk = tid + j * 256;
      int wr = chunk >> 5, wc4 = (chunk & 31) * 4;
      *(float4*)(&Ws[wr][wc4]) =
          *(const float4*)(W + (size_t)(kt + wr) * nout + col0 + wc4);
    }
    __syncthreads();
#pragma unroll
    for (int kk = 0; kk < 8; ++kk) {
      const float4 wv0 = *(const float4*)(&Ws[kk * 4 + 0][c0]);
      const float4 wv1 = *(const float4*)(&Ws[kk * 4 + 1][c0]);
      const float4 wv2 = *(const float4*)(&Ws[kk * 4 + 2][c0]);
      const float4 wv3 = *(const float4*)(&Ws[kk * 4 + 3][c0]);
#pragma unroll
      for (int i = 0; i < 8; ++i) {
        const float4 av = *(const float4*)(&As[r0 + i][kk * 4]);
        acc[i][0] += av.x * wv0.x + av.y * wv1.x + av.z * wv2.x + av.w * wv3.x;
        acc[i][1] += av.x * wv0.y + av.y * wv1.y + av.z * wv2.y + av.w * wv3.y;
        acc[i][2] += av.x * wv0.z + av.y * wv1.z + av.z * wv2.z + av.w * wv3.z;
        acc[i][3] += av.x * wv0.w + av.y * wv1.w + av.z * wv2.w + av.w * wv3.w;
      }
    }
    __syncthreads();
  }
#pragma unroll
  for (int i = 0; i < 8; ++i) {
    int gr = row0 + r0 + i;
    if (gr < nRows) {
      float4 v = make_float4(acc[i][0], acc[i][1], acc[i][2], acc[i][3]);
      *(float4*)(out + (size_t)gr * nout + col0 + c0) = v;
    }
  }
}

// ------------------------------------------------- fused GCN aggregation
__global__ __launch_bounds__(256) void agg_k(const int* __restrict__ rowptr,
                                             const int* __restrict__ csr_eid,
                                             const int* __restrict__ src0,
                                             const float* __restrict__ dis,
                                             const float* __restrict__ hw,
                                             const float* __restrict__ bias,
                                             float* __restrict__ out, int N) {
  int i = (blockIdx.x * 256 + threadIdx.x) >> 6;
  if (i >= N) return;
  int l = threadIdx.x & 63;
  const float di = dis[i];
  const float2 bb = *(const float2*)(bias + l * 2);
  float2 acc = *(const float2*)(hw + (size_t)i * 128 + l * 2);
  float sc = di * di;
  acc.x *= sc; acc.y *= sc;
  int e = rowptr[i], e1 = rowptr[i + 1];
  for (; e + 1 < e1; e += 2) {
    int eA = csr_eid[e], eB = csr_eid[e + 1];
    int sA = src0[eA], sB = src0[eB];
    float cA = dis[sA] * di, cB = dis[sB] * di;
    const float2 vA = *(const float2*)(hw + (size_t)sA * 128 + l * 2);
    const float2 vB = *(const float2*)(hw + (size_t)sB * 128 + l * 2);
    acc.x += vA.x * cA + vB.x * cB;
    acc.y += vA.y * cA + vB.y * cB;
  }
  if (e < e1) {
    int eA = csr_eid[e];
    int sA = src0[eA];
    float cA = dis[sA] * di;
    const float2 vA = *(const float2*)(hw + (size_t)sA * 128 + l * 2);
    acc.x += vA.x * cA;
    acc.y += vA.y * cA;
  }
  acc.x = fmaxf(acc.x + bb.x, 0.f);
  acc.y = fmaxf(acc.y + bb.y, 0.f);
  *(float2*)(out + (size_t)i * 128 + l * 2) = acc;
}

// -------------------------------------------------------------- edge scorer
// 512 threads, 64-edge tiles. Build z1 as split-bf16 in LDS (XOR-swizzled),
// then z1@sW2 via mfma_f32_16x16x32_bf16 (3 products: ah*bh + ah*bl + al*bh).
// Wave w owns output rows mb=w&3 (16) x cols half=w>>2 (4x16). B-fragments
// read directly from L2-resident Wth/Wtl (128KB). 3 barriers per tile.
__global__ __launch_bounds__(512, 4) void scorer_k(
    const float* __restrict__ Amat, const float* __restrict__ Bmat,
    const int* __restrict__ csr_eid, const int* __restrict__ src0,
    const int* __restrict__ tgt0, const float* __restrict__ sb1,
    const unsigned short* __restrict__ Wth,
    const unsigned short* __restrict__ Wtl,
    const float* __restrict__ sb2, const float* __restrict__ sW3,
    const float* __restrict__ sb3, float* __restrict__ score, int E) {
  __shared__ unsigned short z1h[64][256];   // 32 KB (bf16 hi), XOR-swizzled
  __shared__ unsigned short z1l[64][256];   // 32 KB (bf16 lo residual)
  __shared__ float psum[2][64];
  const int tid  = threadIdx.x;
  const int lane = tid & 63;
  const int wv   = tid >> 6;      // 0..7
  const int mb   = wv & 3;        // 16-row output block of this wave
  const int half = wv >> 2;       // which 4 col-blocks (0: n<64, 1: n>=64)
  const int l15  = lane & 15;
  const int l4   = lane >> 4;     // k-quarter / row-quarter
  const float4 bb  = *(const float4*)(sb1 + lane * 4);
  const float sb3s = sb3[0];
  float sb2q[4], w3q[4];
#pragma unroll
  for (int q = 0; q < 4; ++q) {
    int col = (half * 4 + q) * 16 + l15;
    sb2q[q] = sb2[col];
    w3q[q]  = sW3[col];
  }
  char* z1h_b = (char*)&z1h[0][0];
  char* z1l_b = (char*)&z1l[0][0];

  for (int g = 0; g < SCORER_G; ++g) {
    const int e0 = (blockIdx.x * SCORER_G + g) * 64;
    if (e0 >= E) break;                     // uniform across block

    // ---- build z1 tile (8 edges/wave; one float4 slice per lane per edge)
#pragma unroll
    for (int j = 0; j < 8; ++j) {
      int row = wv * 8 + j;
      int e = e0 + row;
      if (e >= E) e = E - 1;                // clamp reads; store guarded later
      int eid = csr_eid[e];
      int s = src0[eid], t = tgt0[eid];
      float4 a = *(const float4*)(Amat + (size_t)s * 256 + lane * 4);
      float4 b = *(const float4*)(Bmat + (size_t)t * 256 + lane * 4);
      float z0 = fmaxf(a.x + b.x + bb.x, 0.f);
      float z1v = fmaxf(a.y + b.y + bb.y, 0.f);
      float z2v = fmaxf(a.z + b.z + bb.z, 0.f);
      float z3v = fmaxf(a.w + b.w + bb.w, 0.f);
      ushort4 hp, lp;
      hp.x = f2bf(z0);  lp.x = f2bf(z0 - bf2f(hp.x));
      hp.y = f2bf(z1v); lp.y = f2bf(z1v - bf2f(hp.y));
      hp.z = f2bf(z2v); lp.z = f2bf(z2v - bf2f(hp.z));
      hp.w = f2bf(z3v); lp.w = f2bf(z3v - bf2f(hp.w));
      int bofs = (row * 512 + lane * 8) ^ ((row & 7) << 4);   // T2 swizzle
      *(ushort4*)(z1h_b + bofs) = hp;
      *(ushort4*)(z1l_b + bofs) = lp;
    }
    __syncthreads();

    // ---- K loop: 8 steps of K=32, 4 col-subtiles, 3 MFMA per (q,kts)
    f32x4 acc0 = {0.f, 0.f, 0.f, 0.f};
    f32x4 acc1 = acc0, acc2 = acc0, acc3 = acc0;
    const int arow = mb * 16 + l15;
    const int aswz = (arow & 7) << 4;
#pragma unroll
    for (int kts = 0; kts < 8; ++kts) {
      int abofs = (arow * 512 + kts * 64 + l4 * 16) ^ aswz;
      bf16x8 ah = *(const bf16x8*)(z1h_b + abofs);
      bf16x8 al = *(const bf16x8*)(z1l_b + abofs);
      const int kof = kts * 32 + l4 * 8;
#define BQ(q)                                                                 \
      {                                                                       \
        int n = (half * 4 + (q)) * 16 + l15;                                  \
        bf16x8 bh = *(const bf16x8*)(Wth + n * 256 + kof);                    \
        bf16x8 bl = *(const bf16x8*)(Wtl + n * 256 + kof);                    \
        acc##q = __builtin_amdgcn_mfma_f32_16x16x32_bf16(al, bh, acc##q, 0, 0, 0); \
        acc##q = __builtin_amdgcn_mfma_f32_16x16x32_bf16(ah, bl, acc##q, 0, 0, 0); \
        acc##q = __builtin_amdgcn_mfma_f32_16x16x32_bf16(ah, bh, acc##q, 0, 0, 0); \
      }
      BQ(0) BQ(1) BQ(2) BQ(3)
#undef BQ
    }

    // ---- epilogue: t[r] = sum_q relu(z2 + sb2) * w3  (lane holds 4 rows x 1 col)
    float t0 = 0.f, t1 = 0.f, t2 = 0.f, t3 = 0.f;
#define EQ(q)                                                   \
    t0 += fmaxf(acc##q[0] + sb2q[q], 0.f) * w3q[q];             \
    t1 += fmaxf(acc##q[1] + sb2q[q], 0.f) * w3q[q];             \
    t2 += fmaxf(acc##q[2] + sb2q[q], 0.f) * w3q[q];             \
    t3 += fmaxf(acc##q[3] + sb2q[q], 0.f) * w3q[q];
    EQ(0) EQ(1) EQ(2) EQ(3)
#undef EQ
#pragma unroll
    for (int m = 8; m >= 1; m >>= 1) {      // reduce 16 col-lanes
      t0 += __shfl_xor(t0, m, 64);
      t1 += __shfl_xor(t1, m, 64);
      t2 += __shfl_xor(t2, m, 64);
      t3 += __shfl_xor(t3, m, 64);
    }
    if (l15 == 0) {                          // rows mb*16 + l4*4 + r
      int rb = mb * 16 + l4 * 4;
      psum[half][rb + 0] = t0;
      psum[half][rb + 1] = t1;
      psum[half][rb + 2] = t2;
      psum[half][rb + 3] = t3;
    }
    __syncthreads();
    if (tid < 64) {
      float v = psum[0][tid] + psum[1][tid] + sb3s;
      v = fminf(fmaxf(v, -1e6f), 1e6f);
      if (v != v) v = 0.f;
      int e = e0 + tid;
      if (e < E) score[csr_eid[e]] = v;
    }
    __syncthreads();                         // z1/psum reuse next tile
  }
}

// ------------------------------------------------------------------ launch

extern "C" void kernel_launch(void* const* d_in, const int* in_sizes, int n_in,
                              void* d_out, int out_size, void* d_ws, size_t ws_size,
                              hipStream_t stream) {
  const float* x   = (const float*)d_in[0];
  const int*   ei  = (const int*)d_in[1];
  const float* W1  = (const float*)d_in[2];
  const float* b1  = (const float*)d_in[3];
  const float* W2  = (const float*)d_in[4];
  const float* b2  = (const float*)d_in[5];
  const float* W3  = (const float*)d_in[6];
  const float* b3  = (const float*)d_in[7];
  const float* sW1 = (const float*)d_in[8];
  const float* sb1 = (const float*)d_in[9];
  const float* sW2 = (const float*)d_in[10];
  const float* sb2 = (const float*)d_in[11];
  const float* sW3 = (const float*)d_in[12];
  const float* sb3 = (const float*)d_in[13];

  const int N = in_sizes[0] / 128;   // 100000
  const int E = in_sizes[1] / 2;     // 1600000
  const int* src0 = ei;
  const int* tgt0 = ei + E;

  float* out_score = (float*)d_out;
  float* out_emb   = out_score + E;   // output order: (score, node_embs)

  // ws arena (floats):
  //   dis[N] | rowptr[N+4] | csr_eid[E] | Abuf[N*256] | Bbuf[N*256]
  //   | Wth[128*256 bf16] | Wtl[128*256 bf16]
  // cursor/bsum overlay the start of Abuf (dead before Abuf's first write).
  float* ws = (float*)d_ws;
  float* dis     = ws;
  int*   rowptr  = (int*)(dis + N);
  int*   csr_eid = rowptr + (N + 4);
  float* Abuf    = (float*)(csr_eid + E);
  float* Bbuf    = Abuf + (size_t)N * 256;
  unsigned short* Wth = (unsigned short*)(Bbuf + (size_t)N * 256);
  unsigned short* Wtl = Wth + 128 * 256;
  int*   cursor  = (int*)Abuf;
  int*   bsum    = cursor + N;
  float* hw      = Abuf;              // layer scratch (first N*128 of Abuf)

  const dim3 blk(256);
  const int gN  = (N + 255) / 256;    // 391 (= nb for scan)
  const int gE  = (E + 255) / 256;
  const int gRows = (N + 63) / 64;
  const int gAgg  = (N * 64 + 255) / 256;
  const int nT64  = (E + 63) / 64;
  const int gScore = (nT64 + SCORER_G - 1) / SCORER_G;

  // ---- CSR build: deg -> rowptr -> cursor/dis -> csr_eid
  zero_i32<<<gN, blk, 0, stream>>>(cursor, N);          // cursor = deg
  deg_count<<<gE, blk, 0, stream>>>(tgt0, cursor, E);
  scan1<<<gN, blk, 0, stream>>>(cursor, rowptr, bsum, N);
  scan2<<<1, 512, 0, stream>>>(bsum, gN);
  scan3<<<gN, blk, 0, stream>>>(rowptr, cursor, bsum, dis, N);
  fill_k<<<gE, blk, 0, stream>>>(tgt0, cursor, csr_eid, E);

  // ---- scorer W2 transpose+split (tiny; L2-hot by scorer time)
  wsplit_k<<<128, blk, 0, stream>>>(sW2, Wth, Wtl);

  // ---- GCN layers (gemm -> fused gather-agg+bias+relu), ping via out_emb
  gemm_k<<<dim3(gRows, 1), blk, 0, stream>>>(x, W1, hw, N, 128);
  agg_k<<<gAgg, blk, 0, stream>>>(rowptr, csr_eid, src0, dis, hw, b1, out_emb, N);
  gemm_k<<<dim3(gRows, 1), blk, 0, stream>>>(out_emb, W2, hw, N, 128);
  agg_k<<<gAgg, blk, 0, stream>>>(rowptr, csr_eid, src0, dis, hw, b2, out_emb, N);
  gemm_k<<<dim3(gRows, 1), blk, 0, stream>>>(out_emb, W3, hw, N, 128);
  agg_k<<<gAgg, blk, 0, stream>>>(rowptr, csr_eid, src0, dis, hw, b3, out_emb, N);

  // ---- scorer prep: A = emb @ sW1[0:128,:], B = emb @ sW1[128:256,:]
  gemm_k<<<dim3(gRows, 2), blk, 0, stream>>>(out_emb, sW1, Abuf, N, 256);
  gemm_k<<<dim3(gRows, 2), blk, 0, stream>>>(out_emb, sW1 + 128 * 256, Bbuf, N, 256);

  // ---- scorer (CSR edge order, MFMA split-bf16 GEMM)
  scorer_k<<<gScore, dim3(512), 0, stream>>>(Abuf, Bbuf, csr_eid, src0, tgt0,
                                             sb1, Wth, Wtl, sb2, sW3, sb3,
                                             out_score, E);
}

// Round 13
// 2657.226 us; speedup vs baseline: 4.5310x; 1.1616x over previous
//
#include <hip/hip_runtime.h>
#include <hip/hip_bf16.h>

// GCN (3 layers) + edge-scorer MLP. N=100000, E=1600000, D=H=128.
// R13 vs R12: scorer K-loop had 64 dependent L2 loads/wave/tile (12.8 GB of
// redundant Wth/Wtl re-reads; VGPR=64 -> no load overlap; MfmaUtil 7.8%).
// Now each wave owns a 16-col slice and holds its B-fragments PERSISTENTLY
// in registers (64 VGPR, loaded once): K-loop = LDS reads + MFMA only.

#define SCORER_G 4   // 64-edge tiles per scorer block

typedef __attribute__((ext_vector_type(8))) short bf16x8;
typedef __attribute__((ext_vector_type(4))) float f32x4;

__device__ __forceinline__ unsigned short f2bf(float x) {   // RNE f32->bf16
  unsigned u = __float_as_uint(x);
  return (unsigned short)((u + 0x7FFFu + ((u >> 16) & 1u)) >> 16);
}
__device__ __forceinline__ float bf2f(unsigned short b) {
  return __uint_as_float(((unsigned)b) << 16);
}

// ---------------------------------------------------------------- prep

__global__ __launch_bounds__(256) void zero_i32(int* __restrict__ p, int n) {
  int i = blockIdx.x * 256 + threadIdx.x;
  if (i < n) p[i] = 0;
}

__global__ __launch_bounds__(256) void deg_count(const int* __restrict__ tgt,
                                                 int* __restrict__ deg, int E) {
  int e = blockIdx.x * 256 + threadIdx.x;
  if (e < E) atomicAdd(&deg[tgt[e]], 1);
}

__global__ __launch_bounds__(256) void scan1(const int* __restrict__ deg,
                                             int* __restrict__ rowptr,
                                             int* __restrict__ bsum, int N) {
  __shared__ int s[256];
  int tid = threadIdx.x;
  int i = blockIdx.x * 256 + tid;
  int v = (i < N) ? deg[i] : 0;
  s[tid] = v;
  __syncthreads();
  for (int off = 1; off < 256; off <<= 1) {
    int t = (tid >= off) ? s[tid - off] : 0;
    __syncthreads();
    s[tid] += t;
    __syncthreads();
  }
  if (i < N) rowptr[i + 1] = s[tid];
  if (tid == 255) bsum[blockIdx.x] = s[255];
}

__global__ __launch_bounds__(512) void scan2(int* __restrict__ bsum, int nb) {
  __shared__ int s[512];
  int tid = threadIdx.x;
  int v = (tid < nb) ? bsum[tid] : 0;
  s[tid] = v;
  __syncthreads();
  for (int off = 1; off < 512; off <<= 1) {
    int t = (tid >= off) ? s[tid - off] : 0;
    __syncthreads();
    s[tid] += t;
    __syncthreads();
  }
  if (tid < nb) bsum[tid] = s[tid] - v;   // exclusive prefix
}

__global__ __launch_bounds__(256) void scan3(int* __restrict__ rowptr,
                                             int* __restrict__ cursor,
                                             const int* __restrict__ bsum,
                                             float* __restrict__ dis, int N) {
  int i = blockIdx.x * 256 + threadIdx.x;
  if (i >= N) return;
  int incl = rowptr[i + 1] + bsum[blockIdx.x];
  rowptr[i + 1] = incl;
  int d = cursor[i];          // cursor currently holds deg
  cursor[i] = incl - d;       // bucket start
  dis[i] = rsqrtf((float)d + 1.0f);
  if (i == 0) rowptr[0] = 0;
}

__global__ __launch_bounds__(256) void fill_k(const int* __restrict__ tgt,
                                              int* __restrict__ cursor,
                                              int* __restrict__ csr_eid, int E) {
  int e = blockIdx.x * 256 + threadIdx.x;
  if (e >= E) return;
  int pos = atomicAdd(&cursor[tgt[e]], 1);
  csr_eid[pos] = e;
}

// transpose+split sW2[256][128] -> Wth/Wtl[128][256] bf16 (hi/lo residual)
__global__ __launch_bounds__(256) void wsplit_k(const float* __restrict__ sW2,
                                                unsigned short* __restrict__ Wth,
                                                unsigned short* __restrict__ Wtl) {
  int id = blockIdx.x * 256 + threadIdx.x;   // id = n*256 + k
  if (id >= 128 * 256) return;
  int n = id >> 8, k = id & 255;
  float v = sW2[k * 128 + n];
  unsigned short h = f2bf(v);
  Wth[id] = h;
  Wtl[id] = f2bf(v - bf2f(h));
}

// ------------------------------------------------------------------- GEMM
__global__ __launch_bounds__(256) void gemm_k(const float* __restrict__ A,
                                              const float* __restrict__ W,
                                              float* __restrict__ out,
                                              int nRows, int nout) {
  __shared__ float As[64][36];
  __shared__ float Ws[32][128];
  const int tid  = threadIdx.x;
  const int row0 = blockIdx.x * 64;
  const int col0 = blockIdx.y * 128;
  const bool full = (row0 + 64 <= nRows);
  const int ty = tid >> 5, tx = tid & 31;
  const int r0 = ty * 8, c0 = tx * 4;
  float acc[8][4] = {};
  for (int kt = 0; kt < 128; kt += 32) {
    if (full) {
#pragma unroll
      for (int j = 0; j < 2; ++j) {
        int chunk = tid + j * 256;
        int r = chunk >> 3, c4 = (chunk & 7) * 4;
        *(float4*)(&As[r][c4]) =
            *(const float4*)(A + (size_t)(row0 + r) * 128 + kt + c4);
      }
    } else {
#pragma unroll
      for (int j = 0; j < 2; ++j) {
        int chunk = tid + j * 256;
        int r = chunk >> 3, c4 = (chunk & 7) * 4;
        float4 v = make_float4(0.f, 0.f, 0.f, 0.f);
        int gr = row0 + r;
        if (gr < nRows) v = *(const float4*)(A + (size_t)gr * 128 + kt + c4);
        *(float4*)(&As[r][c4]) = v;
      }
    }
#pragma unroll
    for (int j = 0; j < 4; ++j) {
      int chunk = tid + j * 256;
      int wr = chunk >> 5, wc4 = (chunk & 31) * 4;
      *(float4*)(&Ws[wr][wc4]) =
          *(const float4*)(W + (size_t)(kt + wr) * nout + col0 + wc4);
    }
    __syncthreads();
#pragma unroll
    for (int kk = 0; kk < 8; ++kk) {
      const float4 wv0 = *(const float4*)(&Ws[kk * 4 + 0][c0]);
      const float4 wv1 = *(const float4*)(&Ws[kk * 4 + 1][c0]);
      const float4 wv2 = *(const float4*)(&Ws[kk * 4 + 2][c0]);
      const float4 wv3 = *(const float4*)(&Ws[kk * 4 + 3][c0]);
#pragma unroll
      for (int i = 0; i < 8; ++i) {
        const float4 av = *(const float4*)(&As[r0 + i][kk * 4]);
        acc[i][0] += av.x * wv0.x + av.y * wv1.x + av.z * wv2.x + av.w * wv3.x;
        acc[i][1] += av.x * wv0.y + av.y * wv1.y + av.z * wv2.y + av.w * wv3.y;
        acc[i][2] += av.x * wv0.z + av.y * wv1.z + av.z * wv2.z + av.w * wv3.z;
        acc[i][3] += av.x * wv0.w + av.y * wv1.w + av.z * wv2.w + av.w * wv3.w;
      }
    }
    __syncthreads();
  }
#pragma unroll
  for (int i = 0; i < 8; ++i) {
    int gr = row0 + r0 + i;
    if (gr < nRows) {
      float4 v = make_float4(acc[i][0], acc[i][1], acc[i][2], acc[i][3]);
      *(float4*)(out + (size_t)gr * nout + col0 + c0) = v;
    }
  }
}

// ------------------------------------------------- fused GCN aggregation
__global__ __launch_bounds__(256) void agg_k(const int* __restrict__ rowptr,
                                             const int* __restrict__ csr_eid,
                                             const int* __restrict__ src0,
                                             const float* __restrict__ dis,
                                             const float* __restrict__ hw,
                                             const float* __restrict__ bias,
                                             float* __restrict__ out, int N) {
  int i = (blockIdx.x * 256 + threadIdx.x) >> 6;
  if (i >= N) return;
  int l = threadIdx.x & 63;
  const float di = dis[i];
  const float2 bb = *(const float2*)(bias + l * 2);
  float2 acc = *(const float2*)(hw + (size_t)i * 128 + l * 2);
  float sc = di * di;
  acc.x *= sc; acc.y *= sc;
  int e = rowptr[i], e1 = rowptr[i + 1];
  for (; e + 1 < e1; e += 2) {
    int eA = csr_eid[e], eB = csr_eid[e + 1];
    int sA = src0[eA], sB = src0[eB];
    float cA = dis[sA] * di, cB = dis[sB] * di;
    const float2 vA = *(const float2*)(hw + (size_t)sA * 128 + l * 2);
    const float2 vB = *(const float2*)(hw + (size_t)sB * 128 + l * 2);
    acc.x += vA.x * cA + vB.x * cB;
    acc.y += vA.y * cA + vB.y * cB;
  }
  if (e < e1) {
    int eA = csr_eid[e];
    int sA = src0[eA];
    float cA = dis[sA] * di;
    const float2 vA = *(const float2*)(hw + (size_t)sA * 128 + l * 2);
    acc.x += vA.x * cA;
    acc.y += vA.y * cA;
  }
  acc.x = fmaxf(acc.x + bb.x, 0.f);
  acc.y = fmaxf(acc.y + bb.y, 0.f);
  *(float2*)(out + (size_t)i * 128 + l * 2) = acc;
}

// -------------------------------------------------------------- edge scorer
// 512 threads, 64-edge tiles. Wave w owns cols [w*16, w*16+16) and holds its
// Wth/Wtl fragments persistently in 64 VGPRs (loaded once). Per tile: build
// z1 (split-bf16, XOR-swizzled LDS), K-loop = 8 kts x 4 rowblocks x
// {2 ds_read_b128 + 3 MFMA}, epilogue shfl-reduce + psum combine.
__global__ __launch_bounds__(512, 4) void scorer_k(
    const float* __restrict__ Amat, const float* __restrict__ Bmat,
    const int* __restrict__ csr_eid, const int* __restrict__ src0,
    const int* __restrict__ tgt0, const float* __restrict__ sb1,
    const unsigned short* __restrict__ Wth,
    const unsigned short* __restrict__ Wtl,
    const float* __restrict__ sb2, const float* __restrict__ sW3,
    const float* __restrict__ sb3, float* __restrict__ score, int E) {
  __shared__ unsigned short z1h[64][256];   // 32 KB (bf16 hi), XOR-swizzled
  __shared__ unsigned short z1l[64][256];   // 32 KB (bf16 lo residual)
  __shared__ float psum[8][64];             // 2 KB
  const int tid  = threadIdx.x;
  const int lane = tid & 63;
  const int wv   = tid >> 6;      // 0..7  (wave id = col-slice id)
  const int l15  = lane & 15;
  const int l4   = lane >> 4;     // k-quarter / row-quarter
  const float4 bb  = *(const float4*)(sb1 + lane * 4);
  const float sb3s = sb3[0];
  const int col   = wv * 16 + l15;           // this lane's output column
  const float sb2c = sb2[col];
  const float w3c  = sW3[col];
  char* z1h_b = (char*)&z1h[0][0];
  char* z1l_b = (char*)&z1l[0][0];

  // ---- persistent B-fragments: 16 x bf16x8 = 64 VGPRs, loaded once
  bf16x8 bh[8], bl[8];
#pragma unroll
  for (int kts = 0; kts < 8; ++kts) {
    size_t wofs = (size_t)col * 256 + kts * 32 + l4 * 8;
    bh[kts] = *(const bf16x8*)(Wth + wofs);
    bl[kts] = *(const bf16x8*)(Wtl + wofs);
  }

  for (int g = 0; g < SCORER_G; ++g) {
    const int e0 = (blockIdx.x * SCORER_G + g) * 64;
    if (e0 >= E) break;                     // uniform across block

    // ---- build z1 tile: 8 edges/wave, batched 2 at a time (4 gathers in flight)
#pragma unroll
    for (int jj = 0; jj < 8; jj += 2) {
      int rowA = wv * 8 + jj, rowB = rowA + 1;
      int eA = e0 + rowA; if (eA >= E) eA = E - 1;
      int eB = e0 + rowB; if (eB >= E) eB = E - 1;
      int eidA = csr_eid[eA], eidB = csr_eid[eB];
      int sA = src0[eidA], tA = tgt0[eidA];
      int sB = src0[eidB], tB = tgt0[eidB];
      float4 aA = *(const float4*)(Amat + (size_t)sA * 256 + lane * 4);
      float4 bA = *(const float4*)(Bmat + (size_t)tA * 256 + lane * 4);
      float4 aB = *(const float4*)(Amat + (size_t)sB * 256 + lane * 4);
      float4 bB = *(const float4*)(Bmat + (size_t)tB * 256 + lane * 4);
      float zA0 = fmaxf(aA.x + bA.x + bb.x, 0.f);
      float zA1 = fmaxf(aA.y + bA.y + bb.y, 0.f);
      float zA2 = fmaxf(aA.z + bA.z + bb.z, 0.f);
      float zA3 = fmaxf(aA.w + bA.w + bb.w, 0.f);
      float zB0 = fmaxf(aB.x + bB.x + bb.x, 0.f);
      float zB1 = fmaxf(aB.y + bB.y + bb.y, 0.f);
      float zB2 = fmaxf(aB.z + bB.z + bb.z, 0.f);
      float zB3 = fmaxf(aB.w + bB.w + bb.w, 0.f);
      ushort4 hp, lp;
      hp.x = f2bf(zA0); lp.x = f2bf(zA0 - bf2f(hp.x));
      hp.y = f2bf(zA1); lp.y = f2bf(zA1 - bf2f(hp.y));
      hp.z = f2bf(zA2); lp.z = f2bf(zA2 - bf2f(hp.z));
      hp.w = f2bf(zA3); lp.w = f2bf(zA3 - bf2f(hp.w));
      int bofsA = (rowA * 512 + lane * 8) ^ ((rowA & 7) << 4);   // T2 swizzle
      *(ushort4*)(z1h_b + bofsA) = hp;
      *(ushort4*)(z1l_b + bofsA) = lp;
      hp.x = f2bf(zB0); lp.x = f2bf(zB0 - bf2f(hp.x));
      hp.y = f2bf(zB1); lp.y = f2bf(zB1 - bf2f(hp.y));
      hp.z = f2bf(zB2); lp.z = f2bf(zB2 - bf2f(hp.z));
      hp.w = f2bf(zB3); lp.w = f2bf(zB3 - bf2f(hp.w));
      int bofsB = (rowB * 512 + lane * 8) ^ ((rowB & 7) << 4);
      *(ushort4*)(z1h_b + bofsB) = hp;
      *(ushort4*)(z1l_b + bofsB) = lp;
    }
    __syncthreads();

    // ---- K loop: all-register B, LDS A. 4 independent acc chains.
    f32x4 acc0 = {0.f, 0.f, 0.f, 0.f};
    f32x4 acc1 = acc0, acc2 = acc0, acc3 = acc0;
#pragma unroll
    for (int kts = 0; kts < 8; ++kts) {
#define RB(rb)                                                                \
      {                                                                       \
        int arow = (rb) * 16 + l15;                                           \
        int abofs = (arow * 512 + kts * 64 + l4 * 16) ^ ((arow & 7) << 4);    \
        bf16x8 ah = *(const bf16x8*)(z1h_b + abofs);                          \
        bf16x8 al = *(const bf16x8*)(z1l_b + abofs);                          \
        acc##rb = __builtin_amdgcn_mfma_f32_16x16x32_bf16(al, bh[kts], acc##rb, 0, 0, 0); \
        acc##rb = __builtin_amdgcn_mfma_f32_16x16x32_bf16(ah, bl[kts], acc##rb, 0, 0, 0); \
        acc##rb = __builtin_amdgcn_mfma_f32_16x16x32_bf16(ah, bh[kts], acc##rb, 0, 0, 0); \
      }
      RB(0) RB(1) RB(2) RB(3)
#undef RB
    }

    // ---- epilogue: per rowblock, t_r = relu(z2+sb2)*w3 reduced over 16 cols
#define EPI(rb)                                                               \
    {                                                                         \
      float t0 = fmaxf(acc##rb[0] + sb2c, 0.f) * w3c;                         \
      float t1 = fmaxf(acc##rb[1] + sb2c, 0.f) * w3c;                         \
      float t2 = fmaxf(acc##rb[2] + sb2c, 0.f) * w3c;                         \
      float t3 = fmaxf(acc##rb[3] + sb2c, 0.f) * w3c;                         \
      _Pragma("unroll")                                                       \
      for (int m = 8; m >= 1; m >>= 1) {                                      \
        t0 += __shfl_xor(t0, m, 64);                                          \
        t1 += __shfl_xor(t1, m, 64);                                          \
        t2 += __shfl_xor(t2, m, 64);                                          \
        t3 += __shfl_xor(t3, m, 64);                                          \
      }                                                                       \
      if (l15 == 0) {                                                         \
        int rbase = (rb) * 16 + l4 * 4;                                       \
        psum[wv][rbase + 0] = t0;                                             \
        psum[wv][rbase + 1] = t1;                                             \
        psum[wv][rbase + 2] = t2;                                             \
        psum[wv][rbase + 3] = t3;                                             \
      }                                                                       \
    }
    EPI(0) EPI(1) EPI(2) EPI(3)
#undef EPI
    __syncthreads();
    if (tid < 64) {
      float v = psum[0][tid] + psum[1][tid] + psum[2][tid] + psum[3][tid] +
                psum[4][tid] + psum[5][tid] + psum[6][tid] + psum[7][tid] +
                sb3s;
      v = fminf(fmaxf(v, -1e6f), 1e6f);
      if (v != v) v = 0.f;
      int e = e0 + tid;
      if (e < E) score[csr_eid[e]] = v;
    }
    __syncthreads();                         // z1/psum reuse next tile
  }
}

// ------------------------------------------------------------------ launch

extern "C" void kernel_launch(void* const* d_in, const int* in_sizes, int n_in,
                              void* d_out, int out_size, void* d_ws, size_t ws_size,
                              hipStream_t stream) {
  const float* x   = (const float*)d_in[0];
  const int*   ei  = (const int*)d_in[1];
  const float* W1  = (const float*)d_in[2];
  const float* b1  = (const float*)d_in[3];
  const float* W2  = (const float*)d_in[4];
  const float* b2  = (const float*)d_in[5];
  const float* W3  = (const float*)d_in[6];
  const float* b3  = (const float*)d_in[7];
  const float* sW1 = (const float*)d_in[8];
  const float* sb1 = (const float*)d_in[9];
  const float* sW2 = (const float*)d_in[10];
  const float* sb2 = (const float*)d_in[11];
  const float* sW3 = (const float*)d_in[12];
  const float* sb3 = (const float*)d_in[13];

  const int N = in_sizes[0] / 128;   // 100000
  const int E = in_sizes[1] / 2;     // 1600000
  const int* src0 = ei;
  const int* tgt0 = ei + E;

  float* out_score = (float*)d_out;
  float* out_emb   = out_score + E;   // output order: (score, node_embs)

  // ws arena (floats):
  //   dis[N] | rowptr[N+4] | csr_eid[E] | Abuf[N*256] | Bbuf[N*256]
  //   | Wth[128*256 bf16] | Wtl[128*256 bf16]
  // cursor/bsum overlay the start of Abuf (dead before Abuf's first write).
  float* ws = (float*)d_ws;
  float* dis     = ws;
  int*   rowptr  = (int*)(dis + N);
  int*   csr_eid = rowptr + (N + 4);
  float* Abuf    = (float*)(csr_eid + E);
  float* Bbuf    = Abuf + (size_t)N * 256;
  unsigned short* Wth = (unsigned short*)(Bbuf + (size_t)N * 256);
  unsigned short* Wtl = Wth + 128 * 256;
  int*   cursor  = (int*)Abuf;
  int*   bsum    = cursor + N;
  float* hw      = Abuf;              // layer scratch (first N*128 of Abuf)

  const dim3 blk(256);
  const int gN  = (N + 255) / 256;    // 391 (= nb for scan)
  const int gE  = (E + 255) / 256;
  const int gRows = (N + 63) / 64;
  const int gAgg  = (N * 64 + 255) / 256;
  const int nT64  = (E + 63) / 64;
  const int gScore = (nT64 + SCORER_G - 1) / SCORER_G;

  // ---- CSR build: deg -> rowptr -> cursor/dis -> csr_eid
  zero_i32<<<gN, blk, 0, stream>>>(cursor, N);          // cursor = deg
  deg_count<<<gE, blk, 0, stream>>>(tgt0, cursor, E);
  scan1<<<gN, blk, 0, stream>>>(cursor, rowptr, bsum, N);
  scan2<<<1, 512, 0, stream>>>(bsum, gN);
  scan3<<<gN, blk, 0, stream>>>(rowptr, cursor, bsum, dis, N);
  fill_k<<<gE, blk, 0, stream>>>(tgt0, cursor, csr_eid, E);

  // ---- scorer W2 transpose+split (tiny; L2-hot by scorer time)
  wsplit_k<<<128, blk, 0, stream>>>(sW2, Wth, Wtl);

  // ---- GCN layers (gemm -> fused gather-agg+bias+relu), ping via out_emb
  gemm_k<<<dim3(gRows, 1), blk, 0, stream>>>(x, W1, hw, N, 128);
  agg_k<<<gAgg, blk, 0, stream>>>(rowptr, csr_eid, src0, dis, hw, b1, out_emb, N);
  gemm_k<<<dim3(gRows, 1), blk, 0, stream>>>(out_emb, W2, hw, N, 128);
  agg_k<<<gAgg, blk, 0, stream>>>(rowptr, csr_eid, src0, dis, hw, b2, out_emb, N);
  gemm_k<<<dim3(gRows, 1), blk, 0, stream>>>(out_emb, W3, hw, N, 128);
  agg_k<<<gAgg, blk, 0, stream>>>(rowptr, csr_eid, src0, dis, hw, b3, out_emb, N);

  // ---- scorer prep: A = emb @ sW1[0:128,:], B = emb @ sW1[128:256,:]
  gemm_k<<<dim3(gRows, 2), blk, 0, stream>>>(out_emb, sW1, Abuf, N, 256);
  gemm_k<<<dim3(gRows, 2), blk, 0, stream>>>(out_emb, sW1 + 128 * 256, Bbuf, N, 256);

  // ---- scorer (CSR edge order, MFMA split-bf16, register-resident W)
  scorer_k<<<gScore, dim3(512), 0, stream>>>(Abuf, Bbuf, csr_eid, src0, tgt0,
                                             sb1, Wth, Wtl, sb2, sW3, sb3,
                                             out_score, E);
}